// Round 12
// baseline (181.100 us; speedup 1.0000x reference)
//
#include <hip/hip_runtime.h>
#include <hip/hip_bf16.h>

using f32x4   = __attribute__((ext_vector_type(4))) float;
using short8  = __attribute__((ext_vector_type(8))) short;
using short4v = __attribute__((ext_vector_type(4))) short;

#define LOG2_2PI 2.6514961294723187f   // log2(2*pi)
#define L2E_HALF 0.7213475204444817f   // 0.5*log2(e)
#define HP2 640   // padded phoneme axis (10 x 64-chunks; 1280B encT rows)

__device__ __forceinline__ short bf16bits(float x) {
  unsigned u = __builtin_bit_cast(unsigned, x);
  u = (u + 0x7FFFu + ((u >> 16) & 1u)) >> 16;   // RNE; inputs are finite
  return (short)u;
}
__device__ __forceinline__ float bf16round(float x) {
  unsigned u = __builtin_bit_cast(unsigned, x);
  u = ((u + 0x7FFFu + ((u >> 16) & 1u)) >> 16) << 16;
  return __builtin_bit_cast(float, u);
}

// Kernel 0: packed params pk[b][h] = {c, q2, b2, 0}; b2 = -1e30 for h >= L
// (masking baked in; h in [L, HP2) gives exp2(-inf) = 0 downstream).
__global__ void prep_kernel(const float* __restrict__ dur,
                            const float* __restrict__ vars,
                            const int* __restrict__ lens,
                            f32x4* __restrict__ pk, int H) {
  const int b = blockIdx.x;
  const int l = threadIdx.x;
  const int L = lens[b];
  float run = 0.f;
  for (int h0 = 0; h0 < HP2; h0 += 64) {
    const int h = h0 + l;
    const float d = (h < H) ? dur[(size_t)b * H + h] : 0.f;
    float x = d;
#pragma unroll
    for (int off = 1; off < 64; off <<= 1) {
      float y = __shfl_up(x, off);
      if (l >= off) x += y;
    }
    f32x4 e = (f32x4){0.f, 0.f, -1e30f, 0.f};
    if (h < H) {
      const float v = vars[(size_t)b * H + h];
      e[0] = run + x - 0.5f * d;
      e[1] = L2E_HALF / v;
      e[2] = (h < L) ? -0.5f * (LOG2_2PI + __builtin_amdgcn_logf(v)) : -1e30f;
    }
    pk[(size_t)b * HP2 + h] = e;
    run += __shfl(x, 63);
  }
}

// Kernel 1 (win5): per (b, 32-frame tile) exact per-frame max + exact minimal
// window {h : s > m - 66}. Each thread holds 4 phonemes in REGISTERS (one
// coalesced global read); all score evals are register-resident VALU with
// fully-static unrolled loops. LDS only for the per-frame max reduction.
__launch_bounds__(256, 4)
__global__ void win5_kernel(const f32x4* __restrict__ pk,
                            float* __restrict__ mArr, int* __restrict__ win,
                            int T, int TT) {
  __shared__ float red[256][33];   // [thread][frame] partial maxes, pad 33
  __shared__ float s2[8][32];
  __shared__ float sThr[32];
  __shared__ int   sLoHi[8];

  const int tile = blockIdx.x;
  const int b    = blockIdx.y;
  const int tid  = threadIdx.x;
  const int t0   = tile * 32;

  // 4 phonemes -> registers (coalesced 64B/thread; sentinel past HP2)
  const int hbase = tid * 4;
  f32x4 P[4];
#pragma unroll
  for (int j = 0; j < 4; ++j)
    P[j] = (hbase + j < HP2) ? pk[(size_t)b * HP2 + hbase + j]
                             : (f32x4){0.f, 0.f, -1e30f, 0.f};

  // pass 1: per-frame partial max over this thread's 4 phonemes (pure VALU)
#pragma unroll
  for (int f = 0; f < 32; ++f) {
    const float tA = (float)(t0 + f);
    float m = -3.0e38f;
#pragma unroll
    for (int j = 0; j < 4; ++j) {
      const float dd = tA - P[j][0];
      m = fmaxf(m, fmaf(-dd * dd, P[j][1], P[j][2]));
    }
    red[tid][f] = m;
  }
  __syncthreads();

  // stage 2: 8 groups x 32 frames; each thread reduces 32 partials
  {
    const int f = tid & 31;
    const int g = tid >> 5;
    float m = -3.0e38f;
#pragma unroll
    for (int k = 0; k < 32; ++k) m = fmaxf(m, red[g * 32 + k][f]);
    s2[g][f] = m;
  }
  __syncthreads();

  // stage 3: finalize per-frame max, write mArr + thresholds
  if (tid < 32) {
    float m = s2[0][tid];
#pragma unroll
    for (int g = 1; g < 8; ++g) m = fmaxf(m, s2[g][tid]);
    sThr[tid] = m - 66.f;
    const int t = t0 + tid;
    if (t < T) mArr[(size_t)b * TT * 32 + t] = m;
  }
  __syncthreads();

  // pass 2: exact tile-union window vs final thresholds (register params)
  int lo = 1 << 30, hi = -1;
#pragma unroll
  for (int f = 0; f < 32; ++f) {
    const float thr = sThr[f];
    const float tA = (float)(t0 + f);
#pragma unroll
    for (int j = 0; j < 4; ++j) {
      const float dd = tA - P[j][0];
      const float s = fmaf(-dd * dd, P[j][1], P[j][2]);
      if (s > thr) { lo = min(lo, hbase + j); hi = max(hi, hbase + j); }
    }
  }
#pragma unroll
  for (int off = 1; off < 64; off <<= 1) {
    lo = min(lo, __shfl_xor(lo, off));
    hi = max(hi, __shfl_xor(hi, off));
  }
  if ((tid & 63) == 0) { sLoHi[(tid >> 6) * 2] = lo; sLoHi[(tid >> 6) * 2 + 1] = hi; }
  __syncthreads();
  if (tid == 0) {
    int l = sLoHi[0], h = sLoHi[1];
#pragma unroll
    for (int w = 1; w < 4; ++w) { l = min(l, sLoHi[w * 2]); h = max(h, sLoHi[w * 2 + 1]); }
    if (h < l) { l = 0; h = 0; }
    win[(b * TT + tile) * 2 + 0] = l >> 6;
    win[(b * TT + tile) * 2 + 1] = (h + 64) >> 6;
  }
}

// Kernel 2: enc [B][H][D] f32 -> encT [B][D][HP2] bf16. Chunks wholly beyond
// ceil(L/64)*64 are never read by gup (cHi <= ceil(L/64)) -> skip them.
__global__ void transpose_kernel(const float* __restrict__ enc,
                                 short* __restrict__ encT,
                                 const int* __restrict__ lens,
                                 int H, int D) {
  __shared__ short sT[64][66];
  const int b  = blockIdx.z;
  const int h0 = blockIdx.y * 64;
  const int d0 = blockIdx.x * 64;
  const int Lpad = (lens[b] + 63) & ~63;
  if (h0 >= Lpad) return;
  const int tid = threadIdx.x;

  const int dc = (tid & 15) * 4;
  const int hr = tid >> 4;
#pragma unroll
  for (int ps = 0; ps < 4; ++ps) {
    const int hh = hr + ps * 16;
    const int h  = h0 + hh;
    f32x4 v = (h < H) ? *(const f32x4*)&enc[((size_t)b * H + h) * D + d0 + dc]
                      : (f32x4){0.f, 0.f, 0.f, 0.f};
#pragma unroll
    for (int j = 0; j < 4; ++j) sT[dc + j][hh] = bf16bits(v[j]);
  }
  __syncthreads();

  const int tx4 = (tid & 15) * 4;
  const int ty2 = tid >> 4;
#pragma unroll
  for (int i = 0; i < 4; ++i) {
    const int d = d0 + ty2 + i * 16;
    short4v v;
#pragma unroll
    for (int j = 0; j < 4; ++j) v[j] = sT[ty2 + i * 16][tx4 + j];
    *(short4v*)&encT[((size_t)b * D + d) * HP2 + h0 + tx4] = v;
  }
}

// Main fused kernel: block = (32-frame tile, d-half, batch), 256 threads =
// 4 waves; wave w owns d in [dbase+64w, +64). Exact precomputed window
// (typically 1 chunk) + precomputed per-frame max; params read directly from
// global (L1-broadcast); LDS = weight tile only.
__launch_bounds__(256, 4)
__global__ void gup_kernel(const short* __restrict__ encT,
                           const f32x4* __restrict__ pk,
                           const int* __restrict__ win,
                           const float* __restrict__ mArr,
                           float* __restrict__ out,
                           int T, int TT) {
  constexpr int D  = 512;
  constexpr int AS = 72;           // sA row stride in halves (144B, 16B-aligned)

  __shared__ float sden[32];
  __shared__ short sA[2][32 * AS];

  const int tid   = threadIdx.x;
  const int b     = blockIdx.y;
  const int tIdx  = blockIdx.x >> 1;
  const int t0    = tIdx * 32;
  const int dbase = (blockIdx.x & 1) * 256;

  const int cLo  = win[(b * TT + tIdx) * 2 + 0];
  const int nC   = win[(b * TT + tIdx) * 2 + 1] - cLo;
  const int base = cLo * 64;

  const int tfA = tid >> 3;               // frame 0..31
  const int hs8 = tid & 7;
  const int k8  = hs8 * 8;                // this thread's 8 k-slots
  const float tA = (float)(t0 + tfA);
  const float mA = mArr[(size_t)b * TT * 32 + t0 + tfA];

  const int lane = tid & 63;
  const int wv   = tid >> 6;
  const int l15  = lane & 15;
  const int lq   = lane >> 4;

  f32x4 acc[2][4];
#pragma unroll
  for (int i = 0; i < 2; ++i)
#pragma unroll
    for (int j = 0; j < 4; ++j) acc[i][j] = (f32x4){0.f, 0.f, 0.f, 0.f};

  float denAcc = 0.f;
  const f32x4* pc = pk + (size_t)b * HP2 + base + k8;
  const short* bp = encT + ((size_t)b * D + dbase + wv * 64 + l15) * HP2 + base + lq * 8;

  int p = 0;
  for (int cc = 0; cc < nC; ++cc, p ^= 1) {
    // A tile: w = exp2(score - m), bf16 (RNE); params straight from global
    short8 w;
#pragma unroll
    for (int j = 0; j < 8; ++j) {
      const f32x4 v = pc[cc * 64 + j];
      const float dd = tA - v[0];
      const float pv = __builtin_amdgcn_exp2f(fmaf(-dd * dd, v[1], v[2]) - mA);
      w[j] = bf16bits(pv);
      denAcc += bf16round(pv);
    }
    *(short8*)&sA[p][tfA * AS + k8] = w;
    __syncthreads();

    // two 32-k sub-steps
#pragma unroll
    for (int kh = 0; kh < 2; ++kh) {
      short8 bfv[4];
#pragma unroll
      for (int nt = 0; nt < 4; ++nt)
        bfv[nt] = *(const short8*)(bp + (size_t)nt * 16 * HP2 + cc * 64 + kh * 32);
      short8 af[2];
#pragma unroll
      for (int mt = 0; mt < 2; ++mt)
        af[mt] = *(short8*)&sA[p][(mt * 16 + l15) * AS + kh * 32 + lq * 8];
      // swapped operands: acc holds C[d][t] -> lane gets 4 consecutive d
#pragma unroll
      for (int mt = 0; mt < 2; ++mt)
#pragma unroll
        for (int nt = 0; nt < 4; ++nt)
          acc[mt][nt] = __builtin_amdgcn_mfma_f32_16x16x32_bf16(bfv[nt], af[mt], acc[mt][nt], 0, 0, 0);
    }
    // single barrier per chunk: double-buffered sA handles WAR across iters.
  }

  // denominators: reduce the 8 threads sharing a frame
  {
    float dsum = denAcc;
    dsum += __shfl_xor(dsum, 1);
    dsum += __shfl_xor(dsum, 2);
    dsum += __shfl_xor(dsum, 4);
    if (hs8 == 0) sden[tfA] = dsum;
  }
  __syncthreads();

  // epilogue: normalize and store float4 (4 consecutive d per thread)
#pragma unroll
  for (int mt = 0; mt < 2; ++mt) {
    const int tg = t0 + mt * 16 + l15;
    const float inv = 1.0f / sden[mt * 16 + l15];
    if (tg < T) {
#pragma unroll
      for (int nt = 0; nt < 4; ++nt) {
        f32x4 o;
#pragma unroll
        for (int i = 0; i < 4; ++i) o[i] = acc[mt][nt][i] * inv;
        *(f32x4*)&out[((size_t)b * T + tg) * D + dbase + wv * 64 + nt * 16 + lq * 4] = o;
      }
    }
  }
}

extern "C" void kernel_launch(void* const* d_in, const int* in_sizes, int n_in,
                              void* d_out, int out_size, void* d_ws, size_t ws_size,
                              hipStream_t stream) {
  const float* enc  = (const float*)d_in[0];
  const float* dur  = (const float*)d_in[1];
  const float* vars = (const float*)d_in[2];
  const int*   lens = (const int*)d_in[3];

  const int B = in_sizes[3];
  const int H = in_sizes[1] / B;
  const int D = in_sizes[0] / in_sizes[1];
  const int T = out_size / (B * D);
  const int TT = (T + 31) / 32;
  (void)n_in; (void)ws_size;

  f32x4* pk   = (f32x4*)d_ws;                         // B*HP2 float4
  int*   wn   = (int*)(pk + (size_t)B * HP2);         // B*TT*2
  float* mArr = (float*)(wn + (size_t)B * TT * 2);    // B*TT*32
  short* encT = (short*)(mArr + (size_t)B * TT * 32); // B*D*HP2 bf16 ~= 21 MB

  prep_kernel<<<B, 64, 0, stream>>>(dur, vars, lens, pk, H);

  dim3 wgrid(TT, B);
  win5_kernel<<<wgrid, 256, 0, stream>>>(pk, mArr, wn, T, TT);

  dim3 tgrid(D / 64, HP2 / 64, B);
  transpose_kernel<<<tgrid, 256, 0, stream>>>(enc, encT, lens, H, D);

  dim3 grid(TT * 2, B);
  gup_kernel<<<grid, 256, 0, stream>>>(encT, pk, wn, mArr, (float*)d_out, T, TT);
}

// Round 13
// 80.251 us; speedup vs baseline: 2.2567x; 2.2567x over previous
//
#include <hip/hip_runtime.h>
#include <hip/hip_bf16.h>

using f32x4   = __attribute__((ext_vector_type(4))) float;
using short8  = __attribute__((ext_vector_type(8))) short;
using short4v = __attribute__((ext_vector_type(4))) short;

#define LOG2_2PI 2.6514961294723187f   // log2(2*pi)
#define L2E_HALF 0.7213475204444817f   // 0.5*log2(e)
#define HP2 640   // padded phoneme axis (10 x 64-chunks; 1280B encT rows)

__device__ __forceinline__ short bf16bits(float x) {
  unsigned u = __builtin_bit_cast(unsigned, x);
  u = (u + 0x7FFFu + ((u >> 16) & 1u)) >> 16;   // RNE; inputs are finite
  return (short)u;
}
__device__ __forceinline__ float bf16round(float x) {
  unsigned u = __builtin_bit_cast(unsigned, x);
  u = ((u + 0x7FFFu + ((u >> 16) & 1u)) >> 16) << 16;
  return __builtin_bit_cast(float, u);
}

// Kernel 0: packed params pk[b][h] = {c, q2, b2(masked), 0} for h in [0,HP2),
// plus per-batch aux = {Gmax, q2Min, q2Max, b2Min, b2Max} over valid h (< L).
// b2 = -1e30 baked in for h >= L -> downstream needs no masking at all.
__global__ void prep_kernel(const float* __restrict__ dur,
                            const float* __restrict__ vars,
                            const int* __restrict__ lens,
                            f32x4* __restrict__ pk, float* __restrict__ aux,
                            int H) {
  const int b = blockIdx.x;
  const int l = threadIdx.x;
  const int L = lens[b];
  float run = 0.f, prevD = 0.f;
  float Gmax = 0.f, qMin = 1e30f, qMax = 0.f, bMin = 1e30f, bMax = -1e30f;
  for (int h0 = 0; h0 < HP2; h0 += 64) {
    const int h = h0 + l;
    const float d = (h < H) ? dur[(size_t)b * H + h] : 0.f;
    float x = d;
#pragma unroll
    for (int off = 1; off < 64; off <<= 1) {
      float y = __shfl_up(x, off);
      if (l >= off) x += y;
    }
    float dp = __shfl_up(d, 1);
    if (l == 0) dp = prevD;
    f32x4 e = (f32x4){0.f, 0.f, -1e30f, 0.f};
    if (h < H) {
      const float v = vars[(size_t)b * H + h];
      const float q = L2E_HALF / v;
      const float bc = -0.5f * (LOG2_2PI + __builtin_amdgcn_logf(v));
      e[0] = run + x - 0.5f * d;
      e[1] = q;
      e[2] = (h < L) ? bc : -1e30f;
      if (h < L) {
        qMin = fminf(qMin, q); qMax = fmaxf(qMax, q);
        bMin = fminf(bMin, bc); bMax = fmaxf(bMax, bc);
        if (h >= 1) Gmax = fmaxf(Gmax, 0.5f * (d + dp));  // center gap
      }
    }
    pk[(size_t)b * HP2 + h] = e;
    prevD = __shfl(d, 63);
    run += __shfl(x, 63);
  }
#pragma unroll
  for (int off = 1; off < 64; off <<= 1) {
    qMin = fminf(qMin, __shfl_xor(qMin, off));
    qMax = fmaxf(qMax, __shfl_xor(qMax, off));
    bMin = fminf(bMin, __shfl_xor(bMin, off));
    bMax = fmaxf(bMax, __shfl_xor(bMax, off));
    Gmax = fmaxf(Gmax, __shfl_xor(Gmax, off));
  }
  if (l == 0) {
    float* ax = aux + b * 8;
    ax[0] = Gmax; ax[1] = qMin; ax[2] = qMax; ax[3] = bMin; ax[4] = bMax;
  }
}

// Kernel 1: enc [B][H][D] f32 -> encT [B][D][HP2] bf16. Chunks wholly beyond
// ceil(L/64)*64 are never read by gup (window clamps to <= ceil(L/64) and
// weights for h >= L are exactly 0) -> skip those blocks.
__global__ void transpose_kernel(const float* __restrict__ enc,
                                 short* __restrict__ encT,
                                 const int* __restrict__ lens,
                                 int H, int D) {
  __shared__ short sT[64][66];
  const int b  = blockIdx.z;
  const int h0 = blockIdx.y * 64;
  const int d0 = blockIdx.x * 64;
  const int Lpad = (lens[b] + 63) & ~63;
  if (h0 >= Lpad) return;
  const int tid = threadIdx.x;

  const int dc = (tid & 15) * 4;
  const int hr = tid >> 4;
#pragma unroll
  for (int ps = 0; ps < 4; ++ps) {
    const int hh = hr + ps * 16;
    const int h  = h0 + hh;
    f32x4 v = (h < H) ? *(const f32x4*)&enc[((size_t)b * H + h) * D + d0 + dc]
                      : (f32x4){0.f, 0.f, 0.f, 0.f};
#pragma unroll
    for (int j = 0; j < 4; ++j) sT[dc + j][hh] = bf16bits(v[j]);
  }
  __syncthreads();

  const int tx4 = (tid & 15) * 4;
  const int ty2 = tid >> 4;
#pragma unroll
  for (int i = 0; i < 4; ++i) {
    const int d = d0 + ty2 + i * 16;
    short4v v;
#pragma unroll
    for (int j = 0; j < 4; ++j) v[j] = sT[ty2 + i * 16][tx4 + j];
    *(short4v*)&encT[((size_t)b * D + d) * HP2 + h0 + tx4] = v;
  }
}

// Main fused kernel (R8 structure, verified 77.7us): block = (32-frame tile,
// d-half, batch), 256 threads = 4 waves; wave w owns d in [dbase+64w, +64).
// Conservative radius window via binary search + exact per-chunk skip.
__launch_bounds__(256, 3)
__global__ void gup_kernel(const short* __restrict__ encT,
                           const f32x4* __restrict__ pk,
                           const float* __restrict__ aux,
                           float* __restrict__ out,
                           int T, int TT) {
  constexpr int D  = 512;
  constexpr int AS = 72;           // sA row stride in halves (144B, 16B-aligned)

  __shared__ __align__(16) float sc[HP2], sq[HP2], sb[HP2];
  __shared__ float sden[32];
  __shared__ short sA[2][32 * AS];

  const int tid   = threadIdx.x;
  const int b     = blockIdx.y;
  const int tIdx  = blockIdx.x >> 1;
  const int t0    = tIdx * 32;
  const int dbase = (blockIdx.x & 1) * 256;

  // phase 0: packed params -> LDS (single global stream)
  for (int i = tid; i < HP2; i += 256) {
    const f32x4 v = pk[(size_t)b * HP2 + i];
    sc[i] = v[0]; sq[i] = v[1]; sb[i] = v[2];
  }
  __syncthreads();

  // effective L from sb mask is not needed: use aux + sc directly.
  // window bound (exp2 domain): drop h iff guaranteed score < max - 65 bits
  const float Gmax = aux[b * 8 + 0], qMn = aux[b * 8 + 1], qMx = aux[b * 8 + 2];
  const float bMn  = aux[b * 8 + 3], bMx = aux[b * 8 + 4];
  // recover L: largest h with sb > -1e29; cheap binary search on the mask
  int llo = 0, lhi = HP2;
  while (llo < lhi) { const int mid = (llo + lhi) >> 1; if (sb[mid] > -1e29f) llo = mid + 1; else lhi = mid; }
  const int L = max(llo, 1);

  const float tLo = (float)t0;
  const float tHi = (float)(min(t0 + 31, T - 1));
  const float c0 = sc[0], cL = sc[L - 1];
  const float D0 = fmaxf(0.5f * Gmax, fmaxf(fmaxf(c0 - tLo, tHi - cL), 0.f));
  const float Wr = __fsqrt_rn(((bMx - bMn) + 65.f + qMx * D0 * D0) / qMn);

  // binary search window [hLo, hHi) in monotone centers (broadcast LDS reads)
  int lo = 0, hi = L;
  const float thLo = tLo - Wr;
  while (lo < hi) { const int mid = (lo + hi) >> 1; if (sc[mid] < thLo) lo = mid + 1; else hi = mid; }
  const int hLo = lo;
  int lo2 = hLo, hi2 = L;
  const float thHi = tHi + Wr;
  while (lo2 < hi2) { const int mid = (lo2 + hi2) >> 1; if (sc[mid] <= thHi) lo2 = mid + 1; else hi2 = mid; }
  const int hHi = lo2;
  const int cLo = hLo >> 6;
  const int cHi = (hHi + 63) >> 6;        // 64-wide chunks

  // premax: exact per-frame max over the window (8 lanes/frame, float4 reads)
  const int tfA = tid >> 3;               // frame 0..31
  const int hs8 = tid & 7;
  const float tA = (float)(t0 + tfA);
  float mA = -1e30f;
  for (int h4 = cLo * 64 + hs8 * 4; h4 < cHi * 64; h4 += 32) {
    const f32x4 cv = *(const f32x4*)&sc[h4];
    const f32x4 qv = *(const f32x4*)&sq[h4];
    const f32x4 bv = *(const f32x4*)&sb[h4];
#pragma unroll
    for (int j = 0; j < 4; ++j) {
      const float dd = tA - cv[j];
      mA = fmaxf(mA, fmaf(-dd * dd, qv[j], bv[j]));
    }
  }
  mA = fmaxf(mA, __shfl_xor(mA, 1));
  mA = fmaxf(mA, __shfl_xor(mA, 2));
  mA = fmaxf(mA, __shfl_xor(mA, 4));

  const int lane = tid & 63;
  const int wv   = tid >> 6;              // wave 0..3 -> d base dbase + 64*wv
  const int l15  = lane & 15;
  const int lq   = lane >> 4;

  f32x4 acc[2][4];
#pragma unroll
  for (int i = 0; i < 2; ++i)
#pragma unroll
    for (int j = 0; j < 4; ++j) acc[i][j] = (f32x4){0.f, 0.f, 0.f, 0.f};

  const int k8 = hs8 * 8;                 // this thread's 8 k-slots in sA
  float denAcc = 0.f;
  const short* bp = encT + ((size_t)b * D + dbase + wv * 64 + l15) * HP2 + lq * 8;

  int p = 0;
  for (int cc = cLo; cc < cHi; ++cc) {
    // A tile: unnormalized weights w = exp2(score - m), bf16 (RNE)
    const int hb = cc * 64 + k8;
    const f32x4 cv0 = *(const f32x4*)&sc[hb];
    const f32x4 qv0 = *(const f32x4*)&sq[hb];
    const f32x4 bv0 = *(const f32x4*)&sb[hb];
    const f32x4 cv1 = *(const f32x4*)&sc[hb + 4];
    const f32x4 qv1 = *(const f32x4*)&sq[hb + 4];
    const f32x4 bv1 = *(const f32x4*)&sb[hb + 4];
    short8 w;
    float denAdd = 0.f, pmax = 0.f;
#pragma unroll
    for (int j = 0; j < 4; ++j) {
      const float dd = tA - cv0[j];
      const float pv = __builtin_amdgcn_exp2f(fmaf(-dd * dd, qv0[j], bv0[j]) - mA);
      w[j] = bf16bits(pv);
      denAdd += bf16round(pv);
      pmax = fmaxf(pmax, pv);
    }
#pragma unroll
    for (int j = 0; j < 4; ++j) {
      const float dd = tA - cv1[j];
      const float pv = __builtin_amdgcn_exp2f(fmaf(-dd * dd, qv1[j], bv1[j]) - mA);
      w[4 + j] = bf16bits(pv);
      denAdd += bf16round(pv);
      pmax = fmaxf(pmax, pv);
    }

    // exact chunk skip: all weights < 2^-66 relative -> contributes nothing
    if (!__syncthreads_or(pmax > 1e-20f)) continue;

    denAcc += denAdd;
    *(short8*)&sA[p][tfA * AS + k8] = w;
    __syncthreads();

    // two 32-k sub-steps
#pragma unroll
    for (int kh = 0; kh < 2; ++kh) {
      short8 bfv[4];
#pragma unroll
      for (int nt = 0; nt < 4; ++nt)
        bfv[nt] = *(const short8*)(bp + (size_t)nt * 16 * HP2 + cc * 64 + kh * 32);
      short8 af[2];
#pragma unroll
      for (int mt = 0; mt < 2; ++mt)
        af[mt] = *(short8*)&sA[p][(mt * 16 + l15) * AS + kh * 32 + lq * 8];
      // swapped operands: acc holds C[d][t] -> lane gets 4 consecutive d
#pragma unroll
      for (int mt = 0; mt < 2; ++mt)
#pragma unroll
        for (int nt = 0; nt < 4; ++nt)
          acc[mt][nt] = __builtin_amdgcn_mfma_f32_16x16x32_bf16(bfv[nt], af[mt], acc[mt][nt], 0, 0, 0);
    }
    p ^= 1;   // double-buffered sA; or-barrier + barrier separate reuse
  }

  // denominators: reduce the 8 threads sharing a frame
  {
    float dsum = denAcc;
    dsum += __shfl_xor(dsum, 1);
    dsum += __shfl_xor(dsum, 2);
    dsum += __shfl_xor(dsum, 4);
    if (hs8 == 0) sden[tfA] = dsum;
  }
  __syncthreads();

  // epilogue: normalize and store float4 (4 consecutive d per thread)
#pragma unroll
  for (int mt = 0; mt < 2; ++mt) {
    const int tg = t0 + mt * 16 + l15;
    const float inv = 1.0f / sden[mt * 16 + l15];
    if (tg < T) {
#pragma unroll
      for (int nt = 0; nt < 4; ++nt) {
        f32x4 o;
#pragma unroll
        for (int i = 0; i < 4; ++i) o[i] = acc[mt][nt][i] * inv;
        *(f32x4*)&out[((size_t)b * T + tg) * D + dbase + wv * 64 + nt * 16 + lq * 4] = o;
      }
    }
  }
}

extern "C" void kernel_launch(void* const* d_in, const int* in_sizes, int n_in,
                              void* d_out, int out_size, void* d_ws, size_t ws_size,
                              hipStream_t stream) {
  const float* enc  = (const float*)d_in[0];
  const float* dur  = (const float*)d_in[1];
  const float* vars = (const float*)d_in[2];
  const int*   lens = (const int*)d_in[3];

  const int B = in_sizes[3];
  const int H = in_sizes[1] / B;
  const int D = in_sizes[0] / in_sizes[1];
  const int T = out_size / (B * D);
  const int TT = (T + 31) / 32;
  (void)n_in; (void)ws_size;

  f32x4* pk  = (f32x4*)d_ws;                       // B*HP2 float4
  float* aux = (float*)(pk + (size_t)B * HP2);     // B*8
  short* encT = (short*)(aux + 8 * (size_t)B);     // B*D*HP2 bf16 ~= 21 MB

  prep_kernel<<<B, 64, 0, stream>>>(dur, vars, lens, pk, aux, H);

  dim3 tgrid(D / 64, HP2 / 64, B);
  transpose_kernel<<<tgrid, 256, 0, stream>>>(enc, encT, lens, H, D);

  dim3 grid(TT * 2, B);
  gup_kernel<<<grid, 256, 0, stream>>>(encT, pk, aux, (float*)d_out, T, TT);
}

// Round 14
// 76.111 us; speedup vs baseline: 2.3794x; 1.0544x over previous
//
#include <hip/hip_runtime.h>
#include <hip/hip_bf16.h>

using f32x4   = __attribute__((ext_vector_type(4))) float;
using short8  = __attribute__((ext_vector_type(8))) short;
using short4v = __attribute__((ext_vector_type(4))) short;

#define LOG2_2PI 2.6514961294723187f   // log2(2*pi)
#define L2E_HALF 0.7213475204444817f   // 0.5*log2(e)
#define HP2 640   // padded phoneme axis (10 x 64-chunks; 1280B encT rows)

__device__ __forceinline__ short bf16bits(float x) {
  unsigned u = __builtin_bit_cast(unsigned, x);
  u = (u + 0x7FFFu + ((u >> 16) & 1u)) >> 16;   // RNE; inputs are finite
  return (short)u;
}
__device__ __forceinline__ float bf16round(float x) {
  unsigned u = __builtin_bit_cast(unsigned, x);
  u = ((u + 0x7FFFu + ((u >> 16) & 1u)) >> 16) << 16;
  return __builtin_bit_cast(float, u);
}

// Kernel 0: packed params pk[b][h] = {c, q2, b2(masked), 0} for h in [0,HP2),
// plus per-batch aux = {Gmax, q2Min, q2Max, b2Min, b2Max} over valid h (< L).
__global__ void prep_kernel(const float* __restrict__ dur,
                            const float* __restrict__ vars,
                            const int* __restrict__ lens,
                            f32x4* __restrict__ pk, float* __restrict__ aux,
                            int H) {
  const int b = blockIdx.x;
  const int l = threadIdx.x;
  const int L = lens[b];
  float run = 0.f, prevD = 0.f;
  float Gmax = 0.f, qMin = 1e30f, qMax = 0.f, bMin = 1e30f, bMax = -1e30f;
  for (int h0 = 0; h0 < HP2; h0 += 64) {
    const int h = h0 + l;
    const float d = (h < H) ? dur[(size_t)b * H + h] : 0.f;
    float x = d;
#pragma unroll
    for (int off = 1; off < 64; off <<= 1) {
      float y = __shfl_up(x, off);
      if (l >= off) x += y;
    }
    float dp = __shfl_up(d, 1);
    if (l == 0) dp = prevD;
    f32x4 e = (f32x4){0.f, 0.f, -1e30f, 0.f};
    if (h < H) {
      const float v = vars[(size_t)b * H + h];
      const float q = L2E_HALF / v;
      const float bc = -0.5f * (LOG2_2PI + __builtin_amdgcn_logf(v));
      e[0] = run + x - 0.5f * d;
      e[1] = q;
      e[2] = (h < L) ? bc : -1e30f;
      if (h < L) {
        qMin = fminf(qMin, q); qMax = fmaxf(qMax, q);
        bMin = fminf(bMin, bc); bMax = fmaxf(bMax, bc);
        if (h >= 1) Gmax = fmaxf(Gmax, 0.5f * (d + dp));  // center gap
      }
    }
    pk[(size_t)b * HP2 + h] = e;
    prevD = __shfl(d, 63);
    run += __shfl(x, 63);
  }
#pragma unroll
  for (int off = 1; off < 64; off <<= 1) {
    qMin = fminf(qMin, __shfl_xor(qMin, off));
    qMax = fmaxf(qMax, __shfl_xor(qMax, off));
    bMin = fminf(bMin, __shfl_xor(bMin, off));
    bMax = fmaxf(bMax, __shfl_xor(bMax, off));
    Gmax = fmaxf(Gmax, __shfl_xor(Gmax, off));
  }
  if (l == 0) {
    float* ax = aux + b * 8;
    ax[0] = Gmax; ax[1] = qMin; ax[2] = qMax; ax[3] = bMin; ax[4] = bMax;
  }
}

// Kernel 1 (R7/R8 verified): per (b, 32-frame tile) conservative chunk window
// via binary search over monotone centers. win[(b*TT+tile)] = {cLo, cHi}.
__global__ void win_kernel(const f32x4* __restrict__ pk,
                           const float* __restrict__ aux,
                           const int* __restrict__ lens,
                           int* __restrict__ win, int T, int TT) {
  const int b = blockIdx.x;
  const int L = lens[b];
  const float Gmax = aux[b * 8 + 0], qMn = aux[b * 8 + 1], qMx = aux[b * 8 + 2];
  const float bMn  = aux[b * 8 + 3], bMx = aux[b * 8 + 4];
  const f32x4* pc = pk + (size_t)b * HP2;
  const float c0 = pc[0][0], cL = pc[L - 1][0];
  for (int tile = threadIdx.x; tile < TT; tile += blockDim.x) {
    const float tLo = (float)(tile * 32);
    const float tHi = (float)(min(tile * 32 + 31, T - 1));
    const float D0 = fmaxf(0.5f * Gmax, fmaxf(fmaxf(c0 - tLo, tHi - cL), 0.f));
    const float Wr = __fsqrt_rn(((bMx - bMn) + 65.f + qMx * D0 * D0) / qMn);
    int lo = 0, hi = L;
    const float thLo = tLo - Wr;
    while (lo < hi) { const int mid = (lo + hi) >> 1; if (pc[mid][0] < thLo) lo = mid + 1; else hi = mid; }
    int hLo = lo;
    int lo2 = hLo, hi2 = L;
    const float thHi = tHi + Wr;
    while (lo2 < hi2) { const int mid = (lo2 + hi2) >> 1; if (pc[mid][0] <= thHi) lo2 = mid + 1; else hi2 = mid; }
    int hHi = lo2;
    if (hHi <= hLo) { hLo = max(hLo - 1, 0); hHi = min(hLo + 2, L); }
    win[(b * TT + tile) * 2 + 0] = hLo >> 6;
    win[(b * TT + tile) * 2 + 1] = (hHi + 63) >> 6;
  }
}

// Kernel 2: enc [B][H][D] f32 -> encT [B][D][HP2] bf16. Chunks wholly beyond
// ceil(L/64)*64 are never read by gup -> skip those blocks (verified R13).
__global__ void transpose_kernel(const float* __restrict__ enc,
                                 short* __restrict__ encT,
                                 const int* __restrict__ lens,
                                 int H, int D) {
  __shared__ short sT[64][66];
  const int b  = blockIdx.z;
  const int h0 = blockIdx.y * 64;
  const int d0 = blockIdx.x * 64;
  const int Lpad = (lens[b] + 63) & ~63;
  if (h0 >= Lpad) return;
  const int tid = threadIdx.x;

  const int dc = (tid & 15) * 4;
  const int hr = tid >> 4;
#pragma unroll
  for (int ps = 0; ps < 4; ++ps) {
    const int hh = hr + ps * 16;
    const int h  = h0 + hh;
    f32x4 v = (h < H) ? *(const f32x4*)&enc[((size_t)b * H + h) * D + d0 + dc]
                      : (f32x4){0.f, 0.f, 0.f, 0.f};
#pragma unroll
    for (int j = 0; j < 4; ++j) sT[dc + j][hh] = bf16bits(v[j]);
  }
  __syncthreads();

  const int tx4 = (tid & 15) * 4;
  const int ty2 = tid >> 4;
#pragma unroll
  for (int i = 0; i < 4; ++i) {
    const int d = d0 + ty2 + i * 16;
    short4v v;
#pragma unroll
    for (int j = 0; j < 4; ++j) v[j] = sT[ty2 + i * 16][tx4 + j];
    *(short4v*)&encT[((size_t)b * D + d) * HP2 + h0 + tx4] = v;
  }
}

// Main fused kernel (exact R8-verified structure): block = (32-frame tile,
// d-half, batch), 256 threads = 4 waves; wave w owns d in [dbase+64w, +64).
// Precomputed window (relative-index LDS staging), in-block premax over the
// window, exact per-chunk skip, double-buffered sA.
__launch_bounds__(256, 3)
__global__ void gup_kernel(const short* __restrict__ encT,
                           const f32x4* __restrict__ pk,
                           const int* __restrict__ win,
                           float* __restrict__ out,
                           int T, int TT) {
  constexpr int D  = 512;
  constexpr int AS = 72;           // sA row stride in halves (144B, 16B-aligned)

  __shared__ __align__(16) float sc[HP2], sq[HP2], sb[HP2];
  __shared__ float sden[32];
  __shared__ short sA[2][32 * AS];

  const int tid   = threadIdx.x;
  const int b     = blockIdx.y;
  const int tIdx  = blockIdx.x >> 1;
  const int t0    = tIdx * 32;
  const int dbase = (blockIdx.x & 1) * 256;

  const int cLo = win[(b * TT + tIdx) * 2 + 0];
  const int cHi = win[(b * TT + tIdx) * 2 + 1];
  const int base = cLo * 64;
  const int nC   = cHi - cLo;
  const int W64  = nC * 64;

  // phase 0: windowed packed params -> LDS (relative indexing)
  for (int i = tid; i < W64; i += 256) {
    const f32x4 v = pk[(size_t)b * HP2 + base + i];
    sc[i] = v[0]; sq[i] = v[1]; sb[i] = v[2];
  }
  __syncthreads();

  // premax: exact per-frame max over the window (8 lanes/frame, float4 reads)
  const int tfA = tid >> 3;               // frame 0..31
  const int hs8 = tid & 7;
  const float tA = (float)(t0 + tfA);
  float mA = -1e30f;
  for (int h4 = hs8 * 4; h4 < W64; h4 += 32) {
    const f32x4 cv = *(const f32x4*)&sc[h4];
    const f32x4 qv = *(const f32x4*)&sq[h4];
    const f32x4 bv = *(const f32x4*)&sb[h4];
#pragma unroll
    for (int j = 0; j < 4; ++j) {
      const float dd = tA - cv[j];
      mA = fmaxf(mA, fmaf(-dd * dd, qv[j], bv[j]));
    }
  }
  mA = fmaxf(mA, __shfl_xor(mA, 1));
  mA = fmaxf(mA, __shfl_xor(mA, 2));
  mA = fmaxf(mA, __shfl_xor(mA, 4));

  const int lane = tid & 63;
  const int wv   = tid >> 6;              // wave 0..3 -> d base dbase + 64*wv
  const int l15  = lane & 15;
  const int lq   = lane >> 4;

  f32x4 acc[2][4];
#pragma unroll
  for (int i = 0; i < 2; ++i)
#pragma unroll
    for (int j = 0; j < 4; ++j) acc[i][j] = (f32x4){0.f, 0.f, 0.f, 0.f};

  const int k8 = hs8 * 8;                 // this thread's 8 k-slots in sA
  float denAcc = 0.f;
  const short* bp = encT + ((size_t)b * D + dbase + wv * 64 + l15) * HP2 + base + lq * 8;

  int p = 0;
  for (int cc = 0; cc < nC; ++cc) {
    // A tile: unnormalized weights w = exp2(score - m), bf16 (RNE)
    const int hb = cc * 64 + k8;
    const f32x4 cv0 = *(const f32x4*)&sc[hb];
    const f32x4 qv0 = *(const f32x4*)&sq[hb];
    const f32x4 bv0 = *(const f32x4*)&sb[hb];
    const f32x4 cv1 = *(const f32x4*)&sc[hb + 4];
    const f32x4 qv1 = *(const f32x4*)&sq[hb + 4];
    const f32x4 bv1 = *(const f32x4*)&sb[hb + 4];
    short8 w;
    float denAdd = 0.f, pmax = 0.f;
#pragma unroll
    for (int j = 0; j < 4; ++j) {
      const float dd = tA - cv0[j];
      const float pv = __builtin_amdgcn_exp2f(fmaf(-dd * dd, qv0[j], bv0[j]) - mA);
      w[j] = bf16bits(pv);
      denAdd += bf16round(pv);
      pmax = fmaxf(pmax, pv);
    }
#pragma unroll
    for (int j = 0; j < 4; ++j) {
      const float dd = tA - cv1[j];
      const float pv = __builtin_amdgcn_exp2f(fmaf(-dd * dd, qv1[j], bv1[j]) - mA);
      w[4 + j] = bf16bits(pv);
      denAdd += bf16round(pv);
      pmax = fmaxf(pmax, pv);
    }

    // exact chunk skip: all weights < 2^-66 relative -> contributes nothing
    if (!__syncthreads_or(pmax > 1e-20f)) continue;

    denAcc += denAdd;
    *(short8*)&sA[p][tfA * AS + k8] = w;
    __syncthreads();

    // two 32-k sub-steps
#pragma unroll
    for (int kh = 0; kh < 2; ++kh) {
      short8 bfv[4];
#pragma unroll
      for (int nt = 0; nt < 4; ++nt)
        bfv[nt] = *(const short8*)(bp + (size_t)nt * 16 * HP2 + cc * 64 + kh * 32);
      short8 af[2];
#pragma unroll
      for (int mt = 0; mt < 2; ++mt)
        af[mt] = *(short8*)&sA[p][(mt * 16 + l15) * AS + kh * 32 + lq * 8];
      // swapped operands: acc holds C[d][t] -> lane gets 4 consecutive d
#pragma unroll
      for (int mt = 0; mt < 2; ++mt)
#pragma unroll
        for (int nt = 0; nt < 4; ++nt)
          acc[mt][nt] = __builtin_amdgcn_mfma_f32_16x16x32_bf16(bfv[nt], af[mt], acc[mt][nt], 0, 0, 0);
    }
    p ^= 1;   // double-buffered sA; or-barrier + barrier separate reuse
  }

  // denominators: reduce the 8 threads sharing a frame
  {
    float dsum = denAcc;
    dsum += __shfl_xor(dsum, 1);
    dsum += __shfl_xor(dsum, 2);
    dsum += __shfl_xor(dsum, 4);
    if (hs8 == 0) sden[tfA] = dsum;
  }
  __syncthreads();

  // epilogue: normalize and store float4 (4 consecutive d per thread)
#pragma unroll
  for (int mt = 0; mt < 2; ++mt) {
    const int tg = t0 + mt * 16 + l15;
    const float inv = 1.0f / sden[mt * 16 + l15];
    if (tg < T) {
#pragma unroll
      for (int nt = 0; nt < 4; ++nt) {
        f32x4 o;
#pragma unroll
        for (int i = 0; i < 4; ++i) o[i] = acc[mt][nt][i] * inv;
        *(f32x4*)&out[((size_t)b * T + tg) * D + dbase + wv * 64 + nt * 16 + lq * 4] = o;
      }
    }
  }
}

extern "C" void kernel_launch(void* const* d_in, const int* in_sizes, int n_in,
                              void* d_out, int out_size, void* d_ws, size_t ws_size,
                              hipStream_t stream) {
  const float* enc  = (const float*)d_in[0];
  const float* dur  = (const float*)d_in[1];
  const float* vars = (const float*)d_in[2];
  const int*   lens = (const int*)d_in[3];

  const int B = in_sizes[3];
  const int H = in_sizes[1] / B;
  const int D = in_sizes[0] / in_sizes[1];
  const int T = out_size / (B * D);
  const int TT = (T + 31) / 32;
  (void)n_in; (void)ws_size;

  f32x4* pk  = (f32x4*)d_ws;                       // B*HP2 float4
  float* aux = (float*)(pk + (size_t)B * HP2);     // B*8
  int*   wn  = (int*)(aux + 8 * (size_t)B);        // B*TT*2
  short* encT = (short*)(wn + (size_t)B * TT * 2); // B*D*HP2 bf16 ~= 21 MB

  prep_kernel<<<B, 64, 0, stream>>>(dur, vars, lens, pk, aux, H);

  win_kernel<<<B, 128, 0, stream>>>(pk, aux, lens, wn, T, TT);

  dim3 tgrid(D / 64, HP2 / 64, B);
  transpose_kernel<<<tgrid, 256, 0, stream>>>(enc, encT, lens, H, D);

  dim3 grid(TT * 2, B);
  gup_kernel<<<grid, 256, 0, stream>>>(encT, pk, wn, (float*)d_out, T, TT);
}